// Round 15
// baseline (86.518 us; speedup 1.0000x reference)
//
#include <hip/hip_runtime.h>
#include <hip/hip_bf16.h>

#define B_ 8
#define SPREV 4095
#define S_ 4096
#define E_ 2048
#define H_ 16
#define HD_ 128
#define LOW_ 512
#define NCH 64      // attention s-chunks per batch
#define CHK 64      // positions per chunk

typedef short s8v __attribute__((ext_vector_type(8)));
typedef float f4v __attribute__((ext_vector_type(4)));

__device__ __forceinline__ short f2bf_s(float f) {
  return (short)__bfloat16_as_ushort(__float2bfloat16(f));
}
__device__ __forceinline__ float bf2f(unsigned short h) {
  union { unsigned u; float f; } v; v.u = ((unsigned)h) << 16;
  return v.f;
}

// Zero all accumulation targets + build rope cos/sin table tab2[s][j] (float2).
__global__ __launch_bounds__(256) void init_kernel(float* __restrict__ ws_pre,
                                                   float* __restrict__ out,
                                                   float2* __restrict__ tab2) {
  int i = blockIdx.x * 256 + threadIdx.x;
  if (i < 55296) ws_pre[i] = 0.f;           // Cq,Qc,qr_pre,ckvn,krn,o_heads
  else if (i < 71680) out[i - 55296] = 0.f;
  int s = i >> 6, j = i & 63;               // [s][j] layout: rope loads coalesce
  float invf = powf(10000.0f, -(float)j * (1.0f / 64.0f));
  float sn, cs; sincosf((float)s * invf, &sn, &cs);
  tab2[i] = make_float2(cs, sn);
}

// out[b][n] += sum_k x[b][k] * W[k][n], k in [k0, k0+32).
__global__ __launch_bounds__(128) void matvec8(
    const float* __restrict__ x, int K,
    const float* __restrict__ W0, int N0, float* __restrict__ o0,
    const float* __restrict__ W1, int N1, float* __restrict__ o1,
    const float* __restrict__ W2, int N2, float* __restrict__ o2)
{
  int cb = blockIdx.x;
  int nb0 = N0 >> 7, nb1 = N1 >> 7;
  const float* W; float* o; int N, colbase;
  if (cb < nb0)            { W = W0; o = o0; N = N0; colbase = cb << 7; }
  else if (cb < nb0 + nb1) { W = W1; o = o1; N = N1; colbase = (cb - nb0) << 7; }
  else                     { W = W2; o = o2; N = N2; colbase = (cb - nb0 - nb1) << 7; }
  int col = colbase + threadIdx.x;
  int k0 = blockIdx.y * 32;
  float acc[B_];
  #pragma unroll
  for (int b = 0; b < B_; ++b) acc[b] = 0.f;
  const float* Wp = W + (size_t)k0 * N + col;
  #pragma unroll 8
  for (int k = 0; k < 32; ++k) {
    float wv = Wp[(size_t)k * N];
    #pragma unroll
    for (int b = 0; b < B_; ++b)
      acc[b] = fmaf(x[b * K + k0 + k], wv, acc[b]);   // uniform -> s_load
  }
  #pragma unroll
  for (int b = 0; b < B_; ++b) atomicAdd(&o[b * N + col], acc[b]);
}

// Merged: bx<64 -> qeff slice (h=bx>>2, 128 l's); bx>=64 -> rope scores
// (coalesced: 16 lanes sweep j for one s, shfl reduce). grid (80, 8) x 256.
__global__ __launch_bounds__(256) void qeff_rope_kernel(
    const float* __restrict__ Qc, const float* __restrict__ FU,
    unsigned short* __restrict__ qeff,
    const float* __restrict__ kr_cache, const float* __restrict__ kr_new,
    const float* __restrict__ qr_pre, const float2* __restrict__ tab2,
    float* __restrict__ score_r)
{
  int bx = blockIdx.x, b = blockIdx.y, t = threadIdx.x;
  int g = t >> 4, li = t & 15;               // 16 groups x 16 lanes
  if (bx < 64) {
    int h = bx >> 2, lq = bx & 3;
    __shared__ float qs[HD_];
    if (t < 128) qs[t] = Qc[b * E_ + h * HD_ + t];
    __syncthreads();
    f4v q0 = *(const f4v*)&qs[li * 8];
    f4v q1 = *(const f4v*)&qs[li * 8 + 4];
    #pragma unroll 2
    for (int p = 0; p < 8; ++p) {
      int l = lq * 128 + p * 16 + g;
      const f4v* w4 = (const f4v*)(FU + (size_t)l * (2 * E_) + h * HD_ + li * 8);
      f4v w0 = w4[0], w1 = w4[1];
      float a = w0[0]*q0[0] + w0[1]*q0[1] + w0[2]*q0[2] + w0[3]*q0[3]
              + w1[0]*q1[0] + w1[1]*q1[1] + w1[2]*q1[2] + w1[3]*q1[3];
      a += __shfl_xor(a, 1); a += __shfl_xor(a, 2);
      a += __shfl_xor(a, 4); a += __shfl_xor(a, 8);
      if (li == 0) qeff[(size_t)(b * H_ + h) * LOW_ + l] = (unsigned short)f2bf_s(a);
    }
  } else {
    int s_base = (bx - 64) * 256;
    __shared__ float qr[128];
    if (t < 64) {
      float invf = powf(10000.0f, -(float)t * (1.0f / 64.0f));
      float x1 = qr_pre[b * HD_ + t], x2 = qr_pre[b * HD_ + 64 + t];
      float sn, cs; sincosf(4095.0f * invf, &sn, &cs);
      qr[t]      = x1 * cs - x2 * sn;
      qr[64 + t] = x1 * sn + x2 * cs;
    }
    __syncthreads();
    f4v qa = *(const f4v*)&qr[li * 4];
    f4v qb = *(const f4v*)&qr[64 + li * 4];
    #pragma unroll 2
    for (int p = 0; p < 16; ++p) {
      int s = s_base + p * 16 + g;
      const float* krp = (s == S_ - 1) ? (kr_new + b * HD_)
                                       : (kr_cache + ((size_t)b * SPREV + s) * HD_);
      f4v x1 = *(const f4v*)&krp[li * 4];
      f4v x2 = *(const f4v*)&krp[64 + li * 4];
      const float2* tp = &tab2[(size_t)s * 64 + li * 4];
      float dot = 0.f;
      #pragma unroll
      for (int q = 0; q < 4; ++q) {
        float2 cs2 = tp[q];
        dot += qa[q] * (x1[q] * cs2.x - x2[q] * cs2.y)
             + qb[q] * (x1[q] * cs2.y + x2[q] * cs2.x);
      }
      dot += __shfl_xor(dot, 1); dot += __shfl_xor(dot, 2);
      dot += __shfl_xor(dot, 4); dot += __shfl_xor(dot, 8);
      if (li == 0) score_r[b * S_ + s] = dot;
    }
  }
}

// Flash-decode, one (b, 64-chunk) per block, 8 waves (512 thr).
// Phase A (ALL 8 waves, k-split): wave w = (s-group w&3, k-half w>>2); each
// wave does 8 kk of QK^T into S_lds[kh]. Phase B (wave 0): softmax summing
// both k-halves. Phase C (all 8 waves): PV via MFMA, each wave owns 64 l.
__global__ __launch_bounds__(512) void attn_kernel(
    const float* __restrict__ ckv_cache, const float* __restrict__ ckv_new,
    const unsigned short* __restrict__ qeff, const float* __restrict__ score_r,
    unsigned short* __restrict__ acc_part, float* __restrict__ m_part,
    float* __restrict__ l_part)
{
  int chunk = blockIdx.x, b = blockIdx.y;
  int tid = threadIdx.x;
  int w = tid >> 6, lane = tid & 63;
  int kg = lane >> 4, l16 = lane & 15;
  __shared__ float S_lds[2][16 * 64];       // [k-half][h*64 + (s ^ ((h&7)<<2))]
  __shared__ unsigned short P_lds[16 * 64]; // swizzled: h*64 + (s ^ ((h&7)<<3))

  { // ---- phase A: all 8 waves; k-split halves the per-wave chain ----
    int kh = w >> 2;                         // k-half: kk in [kh*8, kh*8+8)
    int s_loc = (w & 3) * 16 + l16;
    int s = chunk * CHK + s_loc;
    const float* crow = (s == S_ - 1) ? (ckv_new + b * LOW_)
                                      : (ckv_cache + ((size_t)b * SPREV + s) * LOW_);
    f4v acc0 = {0.f, 0.f, 0.f, 0.f};
    f4v acc1 = {0.f, 0.f, 0.f, 0.f};
    const s8v* qf = (const s8v*)(qeff + (size_t)(b * H_ + l16) * LOW_);
    #pragma unroll
    for (int kt = 0; kt < 4; ++kt) {
      #pragma unroll
      for (int half = 0; half < 2; ++half) {
        int kk = kh * 8 + kt * 2 + half;
        s8v a = qf[kk * 4 + kg];
        const float* cp = crow + kk * 32 + kg * 8;
        f4v c0 = *(const f4v*)cp;
        f4v c1 = *(const f4v*)(cp + 4);
        s8v bv;
        bv[0]=f2bf_s(c0[0]); bv[1]=f2bf_s(c0[1]); bv[2]=f2bf_s(c0[2]); bv[3]=f2bf_s(c0[3]);
        bv[4]=f2bf_s(c1[0]); bv[5]=f2bf_s(c1[1]); bv[6]=f2bf_s(c1[2]); bv[7]=f2bf_s(c1[3]);
        if (half == 0)
          acc0 = __builtin_amdgcn_mfma_f32_16x16x32_bf16(a, bv, acc0, 0, 0, 0);
        else
          acc1 = __builtin_amdgcn_mfma_f32_16x16x32_bf16(a, bv, acc1, 0, 0, 0);
      }
    }
    #pragma unroll
    for (int r = 0; r < 4; ++r) {
      int h = kg * 4 + r;
      S_lds[kh][h * 64 + (s_loc ^ ((h & 7) << 2))] = acc0[r] + acc1[r];
    }
  }
  __syncthreads();

  if (w == 0) { // ---- phase B: lane = part*16 + h; part owns 16 s ----
    int h = l16, part = kg;
    float v[16];
    #pragma unroll
    for (int jj = 0; jj < 4; ++jj) {
      int sb = part * 16 + jj * 4;
      f4v s0 = *(const f4v*)&S_lds[0][h * 64 + (sb ^ ((h & 7) << 2))];
      f4v s1 = *(const f4v*)&S_lds[1][h * 64 + (sb ^ ((h & 7) << 2))];
      f4v rv = *(const f4v*)&score_r[b * S_ + chunk * CHK + sb];
      #pragma unroll
      for (int q = 0; q < 4; ++q) v[jj * 4 + q] = (s0[q] + s1[q] + rv[q]) * 0.0625f;
    }
    float m = v[0];
    #pragma unroll
    for (int j = 1; j < 16; ++j) m = fmaxf(m, v[j]);
    m = fmaxf(m, __shfl_xor(m, 16));
    m = fmaxf(m, __shfl_xor(m, 32));
    float lsum = 0.f;
    #pragma unroll
    for (int j = 0; j < 16; ++j) { v[j] = expf(v[j] - m); lsum += v[j]; }
    lsum += __shfl_xor(lsum, 16);
    lsum += __shfl_xor(lsum, 32);
    #pragma unroll
    for (int jj = 0; jj < 8; ++jj) {
      int sb = part * 16 + jj * 2;
      unsigned pk = (unsigned)(unsigned short)f2bf_s(v[jj*2]) |
                    ((unsigned)(unsigned short)f2bf_s(v[jj*2+1]) << 16);
      *(unsigned*)&P_lds[h * 64 + (sb ^ ((h & 7) << 3))] = pk;
    }
    if (part == 0) {
      int idx = (b * NCH + chunk) * H_ + h;
      m_part[idx] = m;
      l_part[idx] = lsum;
    }
  }
  __syncthreads();

  { // ---- phase C: wave w owns l in [w*64, w*64+64) ----
    s8v pa[2];
    const float* rp[2][8];
    #pragma unroll
    for (int kt = 0; kt < 2; ++kt) {
      int so = kt * 32 + kg * 8;
      pa[kt] = *(const s8v*)&P_lds[l16 * 64 + (so ^ ((l16 & 7) << 3))];
      #pragma unroll
      for (int i = 0; i < 8; ++i) {
        int s = chunk * CHK + so + i;
        rp[kt][i] = (s == S_ - 1) ? (ckv_new + b * LOW_)
                                  : (ckv_cache + ((size_t)b * SPREV + s) * LOW_);
      }
    }
    f4v oa[4];
    #pragma unroll
    for (int nt = 0; nt < 4; ++nt) oa[nt] = {0.f, 0.f, 0.f, 0.f};
    #pragma unroll
    for (int nt = 0; nt < 4; ++nt) {
      int l = w * 64 + nt * 16 + l16;
      #pragma unroll
      for (int kt = 0; kt < 2; ++kt) {
        s8v bv;
        #pragma unroll
        for (int i = 0; i < 8; ++i) bv[i] = (short)f2bf_s(rp[kt][i][l]);
        oa[nt] = __builtin_amdgcn_mfma_f32_16x16x32_bf16(pa[kt], bv, oa[nt], 0, 0, 0);
      }
    }
    size_t base = (size_t)(b * NCH + chunk) * H_;
    #pragma unroll
    for (int nt = 0; nt < 4; ++nt) {
      int l = w * 64 + nt * 16 + l16;
      #pragma unroll
      for (int r = 0; r < 4; ++r) {
        int h = kg * 4 + r;
        acc_part[(base + h) * LOW_ + l] = (unsigned short)f2bf_s(oa[nt][r]);
      }
    }
  }
}

// Fused combine + project (unchanged). grid (16,8,8) x 128 thr.
__global__ __launch_bounds__(128) void reduce_proj_kernel(
    const float* __restrict__ m_part, const float* __restrict__ l_part,
    const unsigned short* __restrict__ acc_part, const float* __restrict__ FU,
    float* __restrict__ o_heads)
{
  int h = blockIdx.x, b = blockIdx.y, lz = blockIdx.z, t = threadIdx.x;
  __shared__ float wls[NCH];
  __shared__ float Linv_s;
  __shared__ float pa0[128], pa1[128];
  __shared__ float wl_sh[64];
  if (t < 64) {
    float mc = m_part[(b * NCH + t) * H_ + h];
    float M = mc;
    #pragma unroll
    for (int d = 1; d < 64; d <<= 1) M = fmaxf(M, __shfl_xor(M, d));
    float wc = expf(mc - M);
    float L = l_part[(b * NCH + t) * H_ + h] * wc;
    #pragma unroll
    for (int d = 1; d < 64; d <<= 1) L += __shfl_xor(L, d);
    wls[t] = wc;
    if (t == 0) Linv_s = 1.0f / L;
  }
  __syncthreads();
  {
    int p = t & 31, ch = t >> 5;
    int l0 = lz * 64 + p * 2;
    float a0 = 0.f, a1 = 0.f;
    const unsigned short* ap =
        acc_part + ((size_t)(b * NCH + ch * 16) * H_ + h) * LOW_ + l0;
    #pragma unroll 4
    for (int c = 0; c < 16; ++c) {
      unsigned pk = *(const unsigned*)(ap + (size_t)c * H_ * LOW_);
      float wc = wls[ch * 16 + c];
      a0 = fmaf(bf2f((unsigned short)(pk & 0xffffu)), wc, a0);
      a1 = fmaf(bf2f((unsigned short)(pk >> 16)),     wc, a1);
    }
    pa0[t] = a0; pa1[t] = a1;
  }
  __syncthreads();
  if (t < 32) {
    float inv = Linv_s;
    float s0 = pa0[t] + pa0[t + 32] + pa0[t + 64] + pa0[t + 96];
    float s1 = pa1[t] + pa1[t + 32] + pa1[t + 64] + pa1[t + 96];
    wl_sh[t * 2]     = s0 * inv;
    wl_sh[t * 2 + 1] = s1 * inv;
  }
  __syncthreads();
  {
    float a = 0.f;
    const float* fp = FU + (size_t)(lz * 64) * (2 * E_) + E_ + h * HD_ + t;
    #pragma unroll 4
    for (int l = 0; l < 64; ++l)
      a = fmaf(wl_sh[l], fp[(size_t)l * (2 * E_)], a);
    atomicAdd(&o_heads[(b * H_ + h) * HD_ + t], a);
  }
}

extern "C" void kernel_launch(void* const* d_in, const int* in_sizes, int n_in,
                              void* d_out, int out_size, void* d_ws, size_t ws_size,
                              hipStream_t stream)
{
  const float* x    = (const float*)d_in[0];
  const float* ckvc = (const float*)d_in[1];
  const float* krc  = (const float*)d_in[2];
  const float* Wdq  = (const float*)d_in[3];
  const float* Wuq  = (const float*)d_in[4];
  const float* Wqr  = (const float*)d_in[5];
  const float* Wdkv = (const float*)d_in[6];
  const float* Wkr  = (const float*)d_in[7];
  const float* FU   = (const float*)d_in[8];
  const float* Wo   = (const float*)d_in[9];
  float* out = (float*)d_out;

  char* ws = (char*)d_ws;
  // zeroed prefix (55296 floats):
  float* Cq             = (float*)(ws + 0);        // 65536 B
  float* Qc             = (float*)(ws + 65536);    // 65536 B
  float* qr_pre         = (float*)(ws + 131072);   // 4096 B
  float* ckvn           = (float*)(ws + 135168);   // 16384 B
  float* krn            = (float*)(ws + 151552);   // 4096 B
  float* o_heads        = (float*)(ws + 155648);   // 65536 B  [prefix end 221184]
  unsigned short* qeff  = (unsigned short*)(ws + 221184);  // 131072 B
  float* m_part         = (float*)(ws + 352256);   // 32768 B
  float* l_part         = (float*)(ws + 385024);   // 32768 B
  float* score_r        = (float*)(ws + 417792);   // 131072 B
  unsigned short* accp  = (unsigned short*)(ws + 548864);  // 8388608 B
  float2* tab2          = (float2*)(ws + 8937472); // 2097152 B (total ~11 MB)

  // Zero all atomic targets + build rope table
  init_kernel<<<1024, 256, 0, stream>>>((float*)ws, out, tab2);

  // Cq = x@Wdq ; ckv_new = x@Wdkv ; kr_new = x@Wkr
  matvec8<<<dim3(21, 64), 128, 0, stream>>>(x, E_, Wdq, E_, Cq,
                                            Wdkv, LOW_, ckvn, Wkr, HD_, krn);
  // Qc = Cq@Wuq ; qr_pre = Cq@Wqr
  matvec8<<<dim3(17, 64), 128, 0, stream>>>(Cq, E_, Wuq, E_, Qc,
                                            Wqr, HD_, qr_pre,
                                            (const float*)nullptr, 0, (float*)nullptr);
  qeff_rope_kernel<<<dim3(80, 8), 256, 0, stream>>>(Qc, FU, qeff,
                                                    krc, krn, qr_pre, tab2, score_r);
  attn_kernel<<<dim3(64, 8), 512, 0, stream>>>(ckvc, ckvn, qeff, score_r,
                                               accp, m_part, l_part);
  reduce_proj_kernel<<<dim3(16, 8, 8), 128, 0, stream>>>(m_part, l_part, accp,
                                                         FU, o_heads);
  // out = o_heads @ Wo
  matvec8<<<dim3(16, 64), 128, 0, stream>>>(o_heads, E_, Wo, E_, out,
                                            (const float*)nullptr, 0, (float*)nullptr,
                                            (const float*)nullptr, 0, (float*)nullptr);
}

// Round 16
// 83.108 us; speedup vs baseline: 1.0410x; 1.0410x over previous
//
#include <hip/hip_runtime.h>
#include <hip/hip_bf16.h>

#define B_ 8
#define SPREV 4095
#define S_ 4096
#define E_ 2048
#define H_ 16
#define HD_ 128
#define LOW_ 512
#define NCH 64      // attention s-chunks per batch
#define CHK 64      // positions per chunk
#define L2INV 0.207620506f   // log2(10000)/64

typedef short s8v __attribute__((ext_vector_type(8)));
typedef float f4v __attribute__((ext_vector_type(4)));

__device__ __forceinline__ short f2bf_s(float f) {
  return (short)__bfloat16_as_ushort(__float2bfloat16(f));
}
__device__ __forceinline__ float bf2f(unsigned short h) {
  union { unsigned u; float f; } v; v.u = ((unsigned)h) << 16;
  return v.f;
}

// Zero all accumulation targets (55296 ws floats + 16384 out floats).
__global__ __launch_bounds__(256) void init_kernel(float* __restrict__ ws_pre,
                                                   float* __restrict__ out) {
  int i = blockIdx.x * 256 + threadIdx.x;
  if (i < 55296) ws_pre[i] = 0.f;           // Cq,Qc,qr_pre,ckvn,krn,o_heads
  else if (i < 71680) out[i - 55296] = 0.f;
}

// out[b][n] += sum_k x[b][k] * W[k][n], k in [k0, k0+32).
__global__ __launch_bounds__(128) void matvec8(
    const float* __restrict__ x, int K,
    const float* __restrict__ W0, int N0, float* __restrict__ o0,
    const float* __restrict__ W1, int N1, float* __restrict__ o1,
    const float* __restrict__ W2, int N2, float* __restrict__ o2)
{
  int cb = blockIdx.x;
  int nb0 = N0 >> 7, nb1 = N1 >> 7;
  const float* W; float* o; int N, colbase;
  if (cb < nb0)            { W = W0; o = o0; N = N0; colbase = cb << 7; }
  else if (cb < nb0 + nb1) { W = W1; o = o1; N = N1; colbase = (cb - nb0) << 7; }
  else                     { W = W2; o = o2; N = N2; colbase = (cb - nb0 - nb1) << 7; }
  int col = colbase + threadIdx.x;
  int k0 = blockIdx.y * 32;
  float acc[B_];
  #pragma unroll
  for (int b = 0; b < B_; ++b) acc[b] = 0.f;
  const float* Wp = W + (size_t)k0 * N + col;
  #pragma unroll 8
  for (int k = 0; k < 32; ++k) {
    float wv = Wp[(size_t)k * N];
    #pragma unroll
    for (int b = 0; b < B_; ++b)
      acc[b] = fmaf(x[b * K + k0 + k], wv, acc[b]);   // uniform -> s_load
  }
  #pragma unroll
  for (int b = 0; b < B_; ++b) atomicAdd(&o[b * N + col], acc[b]);
}

// qeff[b,h,l] = sum_d FU[l, h*128+d] * Qc[b, h*128+d]; block = (h*4+lq, b),
// 256 thr = 16 groups x 16 lanes, 128 l's per block. grid (64, 8).
__global__ __launch_bounds__(256) void qeff_kernel(
    const float* __restrict__ Qc, const float* __restrict__ FU,
    unsigned short* __restrict__ qeff)
{
  int bx = blockIdx.x, b = blockIdx.y, t = threadIdx.x;
  int h = bx >> 2, lq = bx & 3;
  int g = t >> 4, li = t & 15;
  __shared__ float qs[HD_];
  if (t < 128) qs[t] = Qc[b * E_ + h * HD_ + t];
  __syncthreads();
  f4v q0 = *(const f4v*)&qs[li * 8];
  f4v q1 = *(const f4v*)&qs[li * 8 + 4];
  #pragma unroll 2
  for (int p = 0; p < 8; ++p) {
    int l = lq * 128 + p * 16 + g;
    const f4v* w4 = (const f4v*)(FU + (size_t)l * (2 * E_) + h * HD_ + li * 8);
    f4v w0 = w4[0], w1 = w4[1];
    float a = w0[0]*q0[0] + w0[1]*q0[1] + w0[2]*q0[2] + w0[3]*q0[3]
            + w1[0]*q1[0] + w1[1]*q1[1] + w1[2]*q1[2] + w1[3]*q1[3];
    a += __shfl_xor(a, 1); a += __shfl_xor(a, 2);
    a += __shfl_xor(a, 4); a += __shfl_xor(a, 8);
    if (li == 0) qeff[(size_t)(b * H_ + h) * LOW_ + l] = (unsigned short)f2bf_s(a);
  }
}

// Flash-decode, one (b, 64-chunk) per block, 8 waves (512 thr).
// Phase A (8 waves, k-split): wave w = (s-group w&3, k-half w>>2), 8 kk each;
// kh==0 waves additionally compute the rope score for their s inline
// (invf via exp2f, 16 sincosf per lane, kg-split j + shfl reduce -> rope_lds).
// Phase B (ALL 8 waves): softmax; wave w owns h in {2w, 2w+1}, 2 s per lane.
// Phase C (8 waves): PV via MFMA, each wave owns 64 l; ckv re-read (L2).
__global__ __launch_bounds__(512) void attn_kernel(
    const float* __restrict__ ckv_cache, const float* __restrict__ ckv_new,
    const unsigned short* __restrict__ qeff,
    const float* __restrict__ kr_cache, const float* __restrict__ kr_new,
    const float* __restrict__ qr_pre,
    unsigned short* __restrict__ acc_part, float* __restrict__ m_part,
    float* __restrict__ l_part)
{
  int chunk = blockIdx.x, b = blockIdx.y;
  int tid = threadIdx.x;
  int w = tid >> 6, lane = tid & 63;
  int kg = lane >> 4, l16 = lane & 15;
  __shared__ float S_lds[2][16 * 64];       // [k-half][h*64 + (s ^ ((h&7)<<2))]
  __shared__ unsigned short P_lds[16 * 64]; // swizzled: h*64 + (s ^ ((h&7)<<3))
  __shared__ float qr_sh[128];
  __shared__ float rope_lds[64];

  // qr rotated at position 4095 (once per block)
  if (tid < 64) {
    float invf = exp2f(-L2INV * (float)tid);
    float x1 = qr_pre[b * HD_ + tid], x2 = qr_pre[b * HD_ + 64 + tid];
    float sn, cs; sincosf(4095.0f * invf, &sn, &cs);
    qr_sh[tid]      = x1 * cs - x2 * sn;
    qr_sh[64 + tid] = x1 * sn + x2 * cs;
  }
  __syncthreads();

  { // ---- phase A: all 8 waves; k-split halves the per-wave chain ----
    int kh = w >> 2;                         // k-half: kk in [kh*8, kh*8+8)
    int s_loc = (w & 3) * 16 + l16;
    int s = chunk * CHK + s_loc;
    const float* crow = (s == S_ - 1) ? (ckv_new + b * LOW_)
                                      : (ckv_cache + ((size_t)b * SPREV + s) * LOW_);
    f4v acc0 = {0.f, 0.f, 0.f, 0.f};
    f4v acc1 = {0.f, 0.f, 0.f, 0.f};
    const s8v* qf = (const s8v*)(qeff + (size_t)(b * H_ + l16) * LOW_);
    #pragma unroll
    for (int kt = 0; kt < 4; ++kt) {
      #pragma unroll
      for (int half = 0; half < 2; ++half) {
        int kk = kh * 8 + kt * 2 + half;
        s8v a = qf[kk * 4 + kg];
        const float* cp = crow + kk * 32 + kg * 8;
        f4v c0 = *(const f4v*)cp;
        f4v c1 = *(const f4v*)(cp + 4);
        s8v bv;
        bv[0]=f2bf_s(c0[0]); bv[1]=f2bf_s(c0[1]); bv[2]=f2bf_s(c0[2]); bv[3]=f2bf_s(c0[3]);
        bv[4]=f2bf_s(c1[0]); bv[5]=f2bf_s(c1[1]); bv[6]=f2bf_s(c1[2]); bv[7]=f2bf_s(c1[3]);
        if (half == 0)
          acc0 = __builtin_amdgcn_mfma_f32_16x16x32_bf16(a, bv, acc0, 0, 0, 0);
        else
          acc1 = __builtin_amdgcn_mfma_f32_16x16x32_bf16(a, bv, acc1, 0, 0, 0);
      }
    }
    #pragma unroll
    for (int r = 0; r < 4; ++r) {
      int h = kg * 4 + r;
      S_lds[kh][h * 64 + (s_loc ^ ((h & 7) << 2))] = acc0[r] + acc1[r];
    }
    if (w < 4) { // rope score for this s: j in [kg*16, kg*16+16), shfl reduce
      const float* krp = (s == S_ - 1) ? (kr_new + b * HD_)
                                       : (kr_cache + ((size_t)b * SPREV + s) * HD_);
      float fs = (float)s;
      float rdot = 0.f;
      #pragma unroll
      for (int q = 0; q < 4; ++q) {
        int j = kg * 16 + q * 4;
        f4v x1 = *(const f4v*)&krp[j];
        f4v x2 = *(const f4v*)&krp[64 + j];
        f4v qa = *(const f4v*)&qr_sh[j];
        f4v qb = *(const f4v*)&qr_sh[64 + j];
        #pragma unroll
        for (int k2 = 0; k2 < 4; ++k2) {
          float invf = exp2f(-L2INV * (float)(j + k2));
          float sn, cs; sincosf(fs * invf, &sn, &cs);
          rdot += qa[k2] * (x1[k2] * cs - x2[k2] * sn)
                + qb[k2] * (x1[k2] * sn + x2[k2] * cs);
        }
      }
      rdot += __shfl_xor(rdot, 16);
      rdot += __shfl_xor(rdot, 32);
      if (kg == 0) rope_lds[s_loc] = rdot;
    }
  }
  __syncthreads();

  { // ---- phase B: all 8 waves; wave w owns h = 2w + (lane>>5), 2 s/lane ----
    int half = lane >> 5;
    int h = w * 2 + half;
    int sl = lane & 31;
    int s0 = sl * 2;
    int c2 = (h & 7) << 2;
    float v0 = (S_lds[0][h * 64 + (s0 ^ c2)] + S_lds[1][h * 64 + (s0 ^ c2)]
                + rope_lds[s0]) * 0.0625f;
    float v1 = (S_lds[0][h * 64 + ((s0 + 1) ^ c2)] + S_lds[1][h * 64 + ((s0 + 1) ^ c2)]
                + rope_lds[s0 + 1]) * 0.0625f;
    float m = fmaxf(v0, v1);
    m = fmaxf(m, __shfl_xor(m, 1));  m = fmaxf(m, __shfl_xor(m, 2));
    m = fmaxf(m, __shfl_xor(m, 4));  m = fmaxf(m, __shfl_xor(m, 8));
    m = fmaxf(m, __shfl_xor(m, 16));
    float e0 = expf(v0 - m), e1 = expf(v1 - m);
    float lsum = e0 + e1;
    lsum += __shfl_xor(lsum, 1);  lsum += __shfl_xor(lsum, 2);
    lsum += __shfl_xor(lsum, 4);  lsum += __shfl_xor(lsum, 8);
    lsum += __shfl_xor(lsum, 16);
    unsigned pk = (unsigned)(unsigned short)f2bf_s(e0) |
                  ((unsigned)(unsigned short)f2bf_s(e1) << 16);
    *(unsigned*)&P_lds[h * 64 + (s0 ^ ((h & 7) << 3))] = pk;
    if (sl == 0) {
      int idx = (b * NCH + chunk) * H_ + h;
      m_part[idx] = m;
      l_part[idx] = lsum;
    }
  }
  __syncthreads();

  { // ---- phase C: wave w owns l in [w*64, w*64+64) ----
    s8v pa[2];
    const float* rp[2][8];
    #pragma unroll
    for (int kt = 0; kt < 2; ++kt) {
      int so = kt * 32 + kg * 8;
      pa[kt] = *(const s8v*)&P_lds[l16 * 64 + (so ^ ((l16 & 7) << 3))];
      #pragma unroll
      for (int i = 0; i < 8; ++i) {
        int s = chunk * CHK + so + i;
        rp[kt][i] = (s == S_ - 1) ? (ckv_new + b * LOW_)
                                  : (ckv_cache + ((size_t)b * SPREV + s) * LOW_);
      }
    }
    f4v oa[4];
    #pragma unroll
    for (int nt = 0; nt < 4; ++nt) oa[nt] = {0.f, 0.f, 0.f, 0.f};
    #pragma unroll
    for (int nt = 0; nt < 4; ++nt) {
      int l = w * 64 + nt * 16 + l16;
      #pragma unroll
      for (int kt = 0; kt < 2; ++kt) {
        s8v bv;
        #pragma unroll
        for (int i = 0; i < 8; ++i) bv[i] = (short)f2bf_s(rp[kt][i][l]);
        oa[nt] = __builtin_amdgcn_mfma_f32_16x16x32_bf16(pa[kt], bv, oa[nt], 0, 0, 0);
      }
    }
    size_t base = (size_t)(b * NCH + chunk) * H_;
    #pragma unroll
    for (int nt = 0; nt < 4; ++nt) {
      int l = w * 64 + nt * 16 + l16;
      #pragma unroll
      for (int r = 0; r < 4; ++r) {
        int h = kg * 4 + r;
        acc_part[(base + h) * LOW_ + l] = (unsigned short)f2bf_s(oa[nt][r]);
      }
    }
  }
}

// Fused combine + project (unchanged). grid (16,8,8) x 128 thr.
__global__ __launch_bounds__(128) void reduce_proj_kernel(
    const float* __restrict__ m_part, const float* __restrict__ l_part,
    const unsigned short* __restrict__ acc_part, const float* __restrict__ FU,
    float* __restrict__ o_heads)
{
  int h = blockIdx.x, b = blockIdx.y, lz = blockIdx.z, t = threadIdx.x;
  __shared__ float wls[NCH];
  __shared__ float Linv_s;
  __shared__ float pa0[128], pa1[128];
  __shared__ float wl_sh[64];
  if (t < 64) {
    float mc = m_part[(b * NCH + t) * H_ + h];
    float M = mc;
    #pragma unroll
    for (int d = 1; d < 64; d <<= 1) M = fmaxf(M, __shfl_xor(M, d));
    float wc = expf(mc - M);
    float L = l_part[(b * NCH + t) * H_ + h] * wc;
    #pragma unroll
    for (int d = 1; d < 64; d <<= 1) L += __shfl_xor(L, d);
    wls[t] = wc;
    if (t == 0) Linv_s = 1.0f / L;
  }
  __syncthreads();
  {
    int p = t & 31, ch = t >> 5;
    int l0 = lz * 64 + p * 2;
    float a0 = 0.f, a1 = 0.f;
    const unsigned short* ap =
        acc_part + ((size_t)(b * NCH + ch * 16) * H_ + h) * LOW_ + l0;
    #pragma unroll 4
    for (int c = 0; c < 16; ++c) {
      unsigned pk = *(const unsigned*)(ap + (size_t)c * H_ * LOW_);
      float wc = wls[ch * 16 + c];
      a0 = fmaf(bf2f((unsigned short)(pk & 0xffffu)), wc, a0);
      a1 = fmaf(bf2f((unsigned short)(pk >> 16)),     wc, a1);
    }
    pa0[t] = a0; pa1[t] = a1;
  }
  __syncthreads();
  if (t < 32) {
    float inv = Linv_s;
    float s0 = pa0[t] + pa0[t + 32] + pa0[t + 64] + pa0[t + 96];
    float s1 = pa1[t] + pa1[t + 32] + pa1[t + 64] + pa1[t + 96];
    wl_sh[t * 2]     = s0 * inv;
    wl_sh[t * 2 + 1] = s1 * inv;
  }
  __syncthreads();
  {
    float a = 0.f;
    const float* fp = FU + (size_t)(lz * 64) * (2 * E_) + E_ + h * HD_ + t;
    #pragma unroll 4
    for (int l = 0; l < 64; ++l)
      a = fmaf(wl_sh[l], fp[(size_t)l * (2 * E_)], a);
    atomicAdd(&o_heads[(b * H_ + h) * HD_ + t], a);
  }
}

extern "C" void kernel_launch(void* const* d_in, const int* in_sizes, int n_in,
                              void* d_out, int out_size, void* d_ws, size_t ws_size,
                              hipStream_t stream)
{
  const float* x    = (const float*)d_in[0];
  const float* ckvc = (const float*)d_in[1];
  const float* krc  = (const float*)d_in[2];
  const float* Wdq  = (const float*)d_in[3];
  const float* Wuq  = (const float*)d_in[4];
  const float* Wqr  = (const float*)d_in[5];
  const float* Wdkv = (const float*)d_in[6];
  const float* Wkr  = (const float*)d_in[7];
  const float* FU   = (const float*)d_in[8];
  const float* Wo   = (const float*)d_in[9];
  float* out = (float*)d_out;

  char* ws = (char*)d_ws;
  // zeroed prefix (55296 floats):
  float* Cq             = (float*)(ws + 0);        // 65536 B
  float* Qc             = (float*)(ws + 65536);    // 65536 B
  float* qr_pre         = (float*)(ws + 131072);   // 4096 B
  float* ckvn           = (float*)(ws + 135168);   // 16384 B
  float* krn            = (float*)(ws + 151552);   // 4096 B
  float* o_heads        = (float*)(ws + 155648);   // 65536 B  [prefix end 221184]
  unsigned short* qeff  = (unsigned short*)(ws + 221184);  // 131072 B
  float* m_part         = (float*)(ws + 352256);   // 32768 B
  float* l_part         = (float*)(ws + 385024);   // 32768 B
  unsigned short* accp  = (unsigned short*)(ws + 417792);  // 8388608 B (~8.8 MB)

  // Zero all atomic targets
  init_kernel<<<280, 256, 0, stream>>>((float*)ws, out);

  // Cq = x@Wdq ; ckv_new = x@Wdkv ; kr_new = x@Wkr
  matvec8<<<dim3(21, 64), 128, 0, stream>>>(x, E_, Wdq, E_, Cq,
                                            Wdkv, LOW_, ckvn, Wkr, HD_, krn);
  // Qc = Cq@Wuq ; qr_pre = Cq@Wqr
  matvec8<<<dim3(17, 64), 128, 0, stream>>>(Cq, E_, Wuq, E_, Qc,
                                            Wqr, HD_, qr_pre,
                                            (const float*)nullptr, 0, (float*)nullptr);
  qeff_kernel<<<dim3(64, 8), 256, 0, stream>>>(Qc, FU, qeff);
  attn_kernel<<<dim3(64, 8), 512, 0, stream>>>(ckvc, ckvn, qeff, krc, krn,
                                               qr_pre, accp, m_part, l_part);
  reduce_proj_kernel<<<dim3(16, 8, 8), 128, 0, stream>>>(m_part, l_part, accp,
                                                         FU, o_heads);
  // out = o_heads @ Wo
  matvec8<<<dim3(16, 64), 128, 0, stream>>>(o_heads, E_, Wo, E_, out,
                                            (const float*)nullptr, 0, (float*)nullptr,
                                            (const float*)nullptr, 0, (float*)nullptr);
}

// Round 17
// 82.806 us; speedup vs baseline: 1.0448x; 1.0036x over previous
//
#include <hip/hip_runtime.h>
#include <hip/hip_bf16.h>

#define B_ 8
#define SPREV 4095
#define S_ 4096
#define E_ 2048
#define H_ 16
#define HD_ 128
#define LOW_ 512
#define NCH 64      // attention s-chunks per batch
#define CHK 64      // positions per chunk
#define L2INV 0.207620506f   // log2(10000)/64

typedef short s8v __attribute__((ext_vector_type(8)));
typedef float f4v __attribute__((ext_vector_type(4)));

__device__ __forceinline__ short f2bf_s(float f) {
  return (short)__bfloat16_as_ushort(__float2bfloat16(f));
}
__device__ __forceinline__ float bf2f(unsigned short h) {
  union { unsigned u; float f; } v; v.u = ((unsigned)h) << 16;
  return v.f;
}

// Zero all accumulation targets (55296 ws floats + 16384 out floats).
__global__ __launch_bounds__(256) void init_kernel(float* __restrict__ ws_pre,
                                                   float* __restrict__ out) {
  int i = blockIdx.x * 256 + threadIdx.x;
  if (i < 55296) ws_pre[i] = 0.f;           // Cq,Qc,qr_pre,ckvn,krn,o_heads
  else if (i < 71680) out[i - 55296] = 0.f;
}

// out[b][n] += sum_k x[b][k] * W[k][n], k in [k0, k0+32).
__global__ __launch_bounds__(128) void matvec8(
    const float* __restrict__ x, int K,
    const float* __restrict__ W0, int N0, float* __restrict__ o0,
    const float* __restrict__ W1, int N1, float* __restrict__ o1,
    const float* __restrict__ W2, int N2, float* __restrict__ o2)
{
  int cb = blockIdx.x;
  int nb0 = N0 >> 7, nb1 = N1 >> 7;
  const float* W; float* o; int N, colbase;
  if (cb < nb0)            { W = W0; o = o0; N = N0; colbase = cb << 7; }
  else if (cb < nb0 + nb1) { W = W1; o = o1; N = N1; colbase = (cb - nb0) << 7; }
  else                     { W = W2; o = o2; N = N2; colbase = (cb - nb0 - nb1) << 7; }
  int col = colbase + threadIdx.x;
  int k0 = blockIdx.y * 32;
  float acc[B_];
  #pragma unroll
  for (int b = 0; b < B_; ++b) acc[b] = 0.f;
  const float* Wp = W + (size_t)k0 * N + col;
  #pragma unroll 8
  for (int k = 0; k < 32; ++k) {
    float wv = Wp[(size_t)k * N];
    #pragma unroll
    for (int b = 0; b < B_; ++b)
      acc[b] = fmaf(x[b * K + k0 + k], wv, acc[b]);   // uniform -> s_load
  }
  #pragma unroll
  for (int b = 0; b < B_; ++b) atomicAdd(&o[b * N + col], acc[b]);
}

// qeff[b,h,l] = sum_d FU[l, h*128+d] * Qc[b, h*128+d]; block = (h*4+lq, b),
// 256 thr = 16 groups x 16 lanes, 128 l's per block. grid (64, 8).
__global__ __launch_bounds__(256) void qeff_kernel(
    const float* __restrict__ Qc, const float* __restrict__ FU,
    unsigned short* __restrict__ qeff)
{
  int bx = blockIdx.x, b = blockIdx.y, t = threadIdx.x;
  int h = bx >> 2, lq = bx & 3;
  int g = t >> 4, li = t & 15;
  __shared__ float qs[HD_];
  if (t < 128) qs[t] = Qc[b * E_ + h * HD_ + t];
  __syncthreads();
  f4v q0 = *(const f4v*)&qs[li * 8];
  f4v q1 = *(const f4v*)&qs[li * 8 + 4];
  #pragma unroll 2
  for (int p = 0; p < 8; ++p) {
    int l = lq * 128 + p * 16 + g;
    const f4v* w4 = (const f4v*)(FU + (size_t)l * (2 * E_) + h * HD_ + li * 8);
    f4v w0 = w4[0], w1 = w4[1];
    float a = w0[0]*q0[0] + w0[1]*q0[1] + w0[2]*q0[2] + w0[3]*q0[3]
            + w1[0]*q1[0] + w1[1]*q1[1] + w1[2]*q1[2] + w1[3]*q1[3];
    a += __shfl_xor(a, 1); a += __shfl_xor(a, 2);
    a += __shfl_xor(a, 4); a += __shfl_xor(a, 8);
    if (li == 0) qeff[(size_t)(b * H_ + h) * LOW_ + l] = (unsigned short)f2bf_s(a);
  }
}

// Flash-decode, one (b, 64-chunk) per block, 8 waves (512 thr).
// Phase A: k-split, BATCH-PREFETCHED loads (4 kk per batch in regs before any
// cvt/MFMA -> ~3x outstanding HBM loads per wave). Phase B: all-wave softmax.
// Phase C: PV via MFMA, 16 scalars batch-loaded per nt before cvt.
__global__ __launch_bounds__(512) void attn_kernel(
    const float* __restrict__ ckv_cache, const float* __restrict__ ckv_new,
    const unsigned short* __restrict__ qeff,
    const float* __restrict__ kr_cache, const float* __restrict__ kr_new,
    const float* __restrict__ qr_pre,
    unsigned short* __restrict__ acc_part, float* __restrict__ m_part,
    float* __restrict__ l_part)
{
  int chunk = blockIdx.x, b = blockIdx.y;
  int tid = threadIdx.x;
  int w = tid >> 6, lane = tid & 63;
  int kg = lane >> 4, l16 = lane & 15;
  __shared__ float S_lds[2][16 * 64];       // [k-half][h*64 + (s ^ ((h&7)<<2))]
  __shared__ unsigned short P_lds[16 * 64]; // swizzled: h*64 + (s ^ ((h&7)<<3))
  __shared__ float qr_sh[128];
  __shared__ float rope_lds[64];

  // qr rotated at position 4095 (once per block)
  if (tid < 64) {
    float invf = exp2f(-L2INV * (float)tid);
    float x1 = qr_pre[b * HD_ + tid], x2 = qr_pre[b * HD_ + 64 + tid];
    float sn, cs; sincosf(4095.0f * invf, &sn, &cs);
    qr_sh[tid]      = x1 * cs - x2 * sn;
    qr_sh[64 + tid] = x1 * sn + x2 * cs;
  }
  __syncthreads();

  { // ---- phase A: all 8 waves; k-split + 4-kk register batch prefetch ----
    int kh = w >> 2;                         // k-half: kk in [kh*8, kh*8+8)
    int s_loc = (w & 3) * 16 + l16;
    int s = chunk * CHK + s_loc;
    const float* crow = (s == S_ - 1) ? (ckv_new + b * LOW_)
                                      : (ckv_cache + ((size_t)b * SPREV + s) * LOW_);
    f4v acc0 = {0.f, 0.f, 0.f, 0.f};
    f4v acc1 = {0.f, 0.f, 0.f, 0.f};
    const s8v* qf = (const s8v*)(qeff + (size_t)(b * H_ + l16) * LOW_);
    #pragma unroll
    for (int bt = 0; bt < 2; ++bt) {
      f4v c0_[4], c1_[4];
      s8v aq[4];
      #pragma unroll
      for (int u = 0; u < 4; ++u) {        // issue 8 c-loads + 4 a-loads first
        int kk = kh * 8 + bt * 4 + u;
        const float* cp = crow + kk * 32 + kg * 8;
        c0_[u] = *(const f4v*)cp;
        c1_[u] = *(const f4v*)(cp + 4);
        aq[u] = qf[kk * 4 + kg];
      }
      #pragma unroll
      for (int u = 0; u < 4; ++u) {        // then convert + MFMA
        s8v bv;
        bv[0]=f2bf_s(c0_[u][0]); bv[1]=f2bf_s(c0_[u][1]);
        bv[2]=f2bf_s(c0_[u][2]); bv[3]=f2bf_s(c0_[u][3]);
        bv[4]=f2bf_s(c1_[u][0]); bv[5]=f2bf_s(c1_[u][1]);
        bv[6]=f2bf_s(c1_[u][2]); bv[7]=f2bf_s(c1_[u][3]);
        if (u & 1)
          acc1 = __builtin_amdgcn_mfma_f32_16x16x32_bf16(aq[u], bv, acc1, 0, 0, 0);
        else
          acc0 = __builtin_amdgcn_mfma_f32_16x16x32_bf16(aq[u], bv, acc0, 0, 0, 0);
      }
    }
    #pragma unroll
    for (int r = 0; r < 4; ++r) {
      int h = kg * 4 + r;
      S_lds[kh][h * 64 + (s_loc ^ ((h & 7) << 2))] = acc0[r] + acc1[r];
    }
    if (w < 4) { // rope score for this s: j in [kg*16, kg*16+16), shfl reduce
      const float* krp = (s == S_ - 1) ? (kr_new + b * HD_)
                                       : (kr_cache + ((size_t)b * SPREV + s) * HD_);
      float fs = (float)s;
      float rdot = 0.f;
      #pragma unroll
      for (int q = 0; q < 4; ++q) {
        int j = kg * 16 + q * 4;
        f4v x1 = *(const f4v*)&krp[j];
        f4v x2 = *(const f4v*)&krp[64 + j];
        f4v qa = *(const f4v*)&qr_sh[j];
        f4v qb = *(const f4v*)&qr_sh[64 + j];
        #pragma unroll
        for (int k2 = 0; k2 < 4; ++k2) {
          float invf = exp2f(-L2INV * (float)(j + k2));
          float sn, cs; sincosf(fs * invf, &sn, &cs);
          rdot += qa[k2] * (x1[k2] * cs - x2[k2] * sn)
                + qb[k2] * (x1[k2] * sn + x2[k2] * cs);
        }
      }
      rdot += __shfl_xor(rdot, 16);
      rdot += __shfl_xor(rdot, 32);
      if (kg == 0) rope_lds[s_loc] = rdot;
    }
  }
  __syncthreads();

  { // ---- phase B: all 8 waves; wave w owns h = 2w + (lane>>5), 2 s/lane ----
    int half = lane >> 5;
    int h = w * 2 + half;
    int sl = lane & 31;
    int s0 = sl * 2;
    int c2 = (h & 7) << 2;
    float v0 = (S_lds[0][h * 64 + (s0 ^ c2)] + S_lds[1][h * 64 + (s0 ^ c2)]
                + rope_lds[s0]) * 0.0625f;
    float v1 = (S_lds[0][h * 64 + ((s0 + 1) ^ c2)] + S_lds[1][h * 64 + ((s0 + 1) ^ c2)]
                + rope_lds[s0 + 1]) * 0.0625f;
    float m = fmaxf(v0, v1);
    m = fmaxf(m, __shfl_xor(m, 1));  m = fmaxf(m, __shfl_xor(m, 2));
    m = fmaxf(m, __shfl_xor(m, 4));  m = fmaxf(m, __shfl_xor(m, 8));
    m = fmaxf(m, __shfl_xor(m, 16));
    float e0 = expf(v0 - m), e1 = expf(v1 - m);
    float lsum = e0 + e1;
    lsum += __shfl_xor(lsum, 1);  lsum += __shfl_xor(lsum, 2);
    lsum += __shfl_xor(lsum, 4);  lsum += __shfl_xor(lsum, 8);
    lsum += __shfl_xor(lsum, 16);
    unsigned pk = (unsigned)(unsigned short)f2bf_s(e0) |
                  ((unsigned)(unsigned short)f2bf_s(e1) << 16);
    *(unsigned*)&P_lds[h * 64 + (s0 ^ ((h & 7) << 3))] = pk;
    if (sl == 0) {
      int idx = (b * NCH + chunk) * H_ + h;
      m_part[idx] = m;
      l_part[idx] = lsum;
    }
  }
  __syncthreads();

  { // ---- phase C: wave w owns l in [w*64, w*64+64), batch 16 loads per nt ----
    s8v pa[2];
    const float* rp[2][8];
    #pragma unroll
    for (int kt = 0; kt < 2; ++kt) {
      int so = kt * 32 + kg * 8;
      pa[kt] = *(const s8v*)&P_lds[l16 * 64 + (so ^ ((l16 & 7) << 3))];
      #pragma unroll
      for (int i = 0; i < 8; ++i) {
        int s = chunk * CHK + so + i;
        rp[kt][i] = (s == S_ - 1) ? (ckv_new + b * LOW_)
                                  : (ckv_cache + ((size_t)b * SPREV + s) * LOW_);
      }
    }
    f4v oa[4];
    #pragma unroll
    for (int nt = 0; nt < 4; ++nt) oa[nt] = {0.f, 0.f, 0.f, 0.f};
    #pragma unroll
    for (int nt = 0; nt < 4; ++nt) {
      int l = w * 64 + nt * 16 + l16;
      float vb0[8], vb1[8];
      #pragma unroll
      for (int i = 0; i < 8; ++i) { vb0[i] = rp[0][i][l]; vb1[i] = rp[1][i][l]; }
      s8v bv0, bv1;
      #pragma unroll
      for (int i = 0; i < 8; ++i) {
        bv0[i] = f2bf_s(vb0[i]);
        bv1[i] = f2bf_s(vb1[i]);
      }
      oa[nt] = __builtin_amdgcn_mfma_f32_16x16x32_bf16(pa[0], bv0, oa[nt], 0, 0, 0);
      oa[nt] = __builtin_amdgcn_mfma_f32_16x16x32_bf16(pa[1], bv1, oa[nt], 0, 0, 0);
    }
    size_t base = (size_t)(b * NCH + chunk) * H_;
    #pragma unroll
    for (int nt = 0; nt < 4; ++nt) {
      int l = w * 64 + nt * 16 + l16;
      #pragma unroll
      for (int r = 0; r < 4; ++r) {
        int h = kg * 4 + r;
        acc_part[(base + h) * LOW_ + l] = (unsigned short)f2bf_s(oa[nt][r]);
      }
    }
  }
}

// Fused combine + project (unchanged). grid (16,8,8) x 128 thr.
__global__ __launch_bounds__(128) void reduce_proj_kernel(
    const float* __restrict__ m_part, const float* __restrict__ l_part,
    const unsigned short* __restrict__ acc_part, const float* __restrict__ FU,
    float* __restrict__ o_heads)
{
  int h = blockIdx.x, b = blockIdx.y, lz = blockIdx.z, t = threadIdx.x;
  __shared__ float wls[NCH];
  __shared__ float Linv_s;
  __shared__ float pa0[128], pa1[128];
  __shared__ float wl_sh[64];
  if (t < 64) {
    float mc = m_part[(b * NCH + t) * H_ + h];
    float M = mc;
    #pragma unroll
    for (int d = 1; d < 64; d <<= 1) M = fmaxf(M, __shfl_xor(M, d));
    float wc = expf(mc - M);
    float L = l_part[(b * NCH + t) * H_ + h] * wc;
    #pragma unroll
    for (int d = 1; d < 64; d <<= 1) L += __shfl_xor(L, d);
    wls[t] = wc;
    if (t == 0) Linv_s = 1.0f / L;
  }
  __syncthreads();
  {
    int p = t & 31, ch = t >> 5;
    int l0 = lz * 64 + p * 2;
    float a0 = 0.f, a1 = 0.f;
    const unsigned short* ap =
        acc_part + ((size_t)(b * NCH + ch * 16) * H_ + h) * LOW_ + l0;
    #pragma unroll 4
    for (int c = 0; c < 16; ++c) {
      unsigned pk = *(const unsigned*)(ap + (size_t)c * H_ * LOW_);
      float wc = wls[ch * 16 + c];
      a0 = fmaf(bf2f((unsigned short)(pk & 0xffffu)), wc, a0);
      a1 = fmaf(bf2f((unsigned short)(pk >> 16)),     wc, a1);
    }
    pa0[t] = a0; pa1[t] = a1;
  }
  __syncthreads();
  if (t < 32) {
    float inv = Linv_s;
    float s0 = pa0[t] + pa0[t + 32] + pa0[t + 64] + pa0[t + 96];
    float s1 = pa1[t] + pa1[t + 32] + pa1[t + 64] + pa1[t + 96];
    wl_sh[t * 2]     = s0 * inv;
    wl_sh[t * 2 + 1] = s1 * inv;
  }
  __syncthreads();
  {
    float a = 0.f;
    const float* fp = FU + (size_t)(lz * 64) * (2 * E_) + E_ + h * HD_ + t;
    #pragma unroll 4
    for (int l = 0; l < 64; ++l)
      a = fmaf(wl_sh[l], fp[(size_t)l * (2 * E_)], a);
    atomicAdd(&o_heads[(b * H_ + h) * HD_ + t], a);
  }
}

extern "C" void kernel_launch(void* const* d_in, const int* in_sizes, int n_in,
                              void* d_out, int out_size, void* d_ws, size_t ws_size,
                              hipStream_t stream)
{
  const float* x    = (const float*)d_in[0];
  const float* ckvc = (const float*)d_in[1];
  const float* krc  = (const float*)d_in[2];
  const float* Wdq  = (const float*)d_in[3];
  const float* Wuq  = (const float*)d_in[4];
  const float* Wqr  = (const float*)d_in[5];
  const float* Wdkv = (const float*)d_in[6];
  const float* Wkr  = (const float*)d_in[7];
  const float* FU   = (const float*)d_in[8];
  const float* Wo   = (const float*)d_in[9];
  float* out = (float*)d_out;

  char* ws = (char*)d_ws;
  // zeroed prefix (55296 floats):
  float* Cq             = (float*)(ws + 0);        // 65536 B
  float* Qc             = (float*)(ws + 65536);    // 65536 B
  float* qr_pre         = (float*)(ws + 131072);   // 4096 B
  float* ckvn           = (float*)(ws + 135168);   // 16384 B
  float* krn            = (float*)(ws + 151552);   // 4096 B
  float* o_heads        = (float*)(ws + 155648);   // 65536 B  [prefix end 221184]
  unsigned short* qeff  = (unsigned short*)(ws + 221184);  // 131072 B
  float* m_part         = (float*)(ws + 352256);   // 32768 B
  float* l_part         = (float*)(ws + 385024);   // 32768 B
  unsigned short* accp  = (unsigned short*)(ws + 417792);  // 8388608 B (~8.8 MB)

  // Zero all atomic targets
  init_kernel<<<280, 256, 0, stream>>>((float*)ws, out);

  // Cq = x@Wdq ; ckv_new = x@Wdkv ; kr_new = x@Wkr
  matvec8<<<dim3(21, 64), 128, 0, stream>>>(x, E_, Wdq, E_, Cq,
                                            Wdkv, LOW_, ckvn, Wkr, HD_, krn);
  // Qc = Cq@Wuq ; qr_pre = Cq@Wqr
  matvec8<<<dim3(17, 64), 128, 0, stream>>>(Cq, E_, Wuq, E_, Qc,
                                            Wqr, HD_, qr_pre,
                                            (const float*)nullptr, 0, (float*)nullptr);
  qeff_kernel<<<dim3(64, 8), 256, 0, stream>>>(Qc, FU, qeff);
  attn_kernel<<<dim3(64, 8), 512, 0, stream>>>(ckvc, ckvn, qeff, krc, krn,
                                               qr_pre, accp, m_part, l_part);
  reduce_proj_kernel<<<dim3(16, 8, 8), 128, 0, stream>>>(m_part, l_part, accp,
                                                         FU, o_heads);
  // out = o_heads @ Wo
  matvec8<<<dim3(16, 64), 128, 0, stream>>>(o_heads, E_, Wo, E_, out,
                                            (const float*)nullptr, 0, (float*)nullptr,
                                            (const float*)nullptr, 0, (float*)nullptr);
}